// Round 1
// baseline (1853.168 us; speedup 1.0000x reference)
//
#include <hip/hip_runtime.h>

// Problem constants
#define B_   8
#define N_   16384
#define C_   256
#define H_   8
#define D_   64
#define HD_  512
#define BN_  (B_ * N_)          // 131072 total rows
#define NF   16384.0f

typedef __attribute__((ext_vector_type(8))) short short8;   // 8 bf16 (4 VGPRs)
typedef __attribute__((ext_vector_type(4))) float f32x4;    // MFMA accumulator

typedef unsigned short bhalf;   // raw bf16 bits

__device__ __forceinline__ bhalf f2bf(float x) {
    union { float f; unsigned u; } v; v.f = x;
    unsigned r = v.u + 0x7fffu + ((v.u >> 16) & 1u);   // RNE
    return (bhalf)(r >> 16);
}
__device__ __forceinline__ float bf2f(bhalf h) {
    union { unsigned u; float f; } v; v.u = ((unsigned)h) << 16;
    return v.f;
}

// ---------------------------------------------------------------------------
// K0: cast + transpose weights:  WT[c][k] = W_sec[k][c_sec]  (c = sec*512+cs)
//     and concat biases (fp32).
// ---------------------------------------------------------------------------
__global__ void cast_w_kernel(const float* __restrict__ Wq, const float* __restrict__ Wk,
                              const float* __restrict__ Wv, const float* __restrict__ bq,
                              const float* __restrict__ bk, const float* __restrict__ bv,
                              bhalf* __restrict__ WT, float* __restrict__ biasCat)
{
    int c = blockIdx.x;              // 0..1535
    int k = threadIdx.x;             // 0..255
    int sec = c >> 9, cs = c & 511;
    const float* W = (sec == 0) ? Wq : (sec == 1 ? Wk : Wv);
    WT[(size_t)c * C_ + k] = f2bf(W[(size_t)k * HD_ + cs]);
    if (k == 0) {
        const float* bb = (sec == 0) ? bq : (sec == 1 ? bk : bv);
        biasCat[c] = bb[cs];
    }
}

// ---------------------------------------------------------------------------
// K1: projection GEMM  out[row, col] = A[row,:] @ W[:, col] + bias
//     grid.x = 12 col-tiles (0..3 -> q, 4..7 -> k, 8..11 -> v), grid.y = 1024 row-tiles
//     Epilogue: bias, per-head L2 norm (q,k), ksum/vsum atomics (k,v), bf16 store.
// ---------------------------------------------------------------------------
__global__ __launch_bounds__(256) void proj_kernel(
    const float* __restrict__ query, const float* __restrict__ source,
    const bhalf* __restrict__ WT, const float* __restrict__ biasCat,
    bhalf* __restrict__ qn, bhalf* __restrict__ kn, bhalf* __restrict__ vv,
    float* __restrict__ ksum, float* __restrict__ vsum)
{
    const int ct = blockIdx.x;           // 0..11
    const int rt = blockIdx.y;           // 0..1023
    const int section = ct >> 2;         // 0=q, 1=k, 2=v
    const int sec_col0 = (ct & 3) * 128; // col offset within 512-wide section
    const int row0 = rt * 128;
    const int b = row0 >> 14;            // 16384 rows per batch

    const float* Abase = (section == 0 ? query : source) + (size_t)row0 * C_;
    const bhalf* Wbase = WT + (size_t)(section * HD_ + sec_col0) * C_;

    __shared__ bhalf As[128 * 32];
    __shared__ bhalf Bs[128 * 32];

    const int tid  = threadIdx.x;
    const int wave = tid >> 6;
    const int lane = tid & 63;
    const int l15  = lane & 15;
    const int quad = lane >> 4;
    const int wm = (wave >> 1) * 64;     // wave row offset in tile
    const int wn = (wave & 1) * 64;      // wave col offset in tile

    f32x4 acc[4][4];
#pragma unroll
    for (int i = 0; i < 4; ++i)
#pragma unroll
        for (int j = 0; j < 4; ++j)
            acc[i][j] = (f32x4)(0.0f);

    const int sr = tid >> 1;             // staging row 0..127
    const int sc = (tid & 1) * 16;       // staging col 0 or 16 (of 32)

    for (int kk = 0; kk < C_; kk += 32) {
        // stage A tile (fp32 global -> bf16 LDS), 16 elems/thread
        {
            const float* src = Abase + (size_t)sr * C_ + kk + sc;
            float tmp[16];
            *(float4*)&tmp[0]  = *(const float4*)(src + 0);
            *(float4*)&tmp[4]  = *(const float4*)(src + 4);
            *(float4*)&tmp[8]  = *(const float4*)(src + 8);
            *(float4*)&tmp[12] = *(const float4*)(src + 12);
            bhalf* dst = &As[sr * 32 + sc];
#pragma unroll
            for (int e = 0; e < 16; ++e) dst[e] = f2bf(tmp[e]);
        }
        // stage B tile (bf16 copy), 16 elems/thread
        {
            const uint4* s4 = (const uint4*)(Wbase + (size_t)sr * C_ + kk + sc);
            uint4* d4 = (uint4*)&Bs[sr * 32 + sc];
            d4[0] = s4[0]; d4[1] = s4[1];
        }
        __syncthreads();

        short8 af[4], bfr[4];
#pragma unroll
        for (int i = 0; i < 4; ++i)
            af[i] = *(const short8*)&As[(wm + i * 16 + l15) * 32 + quad * 8];
#pragma unroll
        for (int j = 0; j < 4; ++j)
            bfr[j] = *(const short8*)&Bs[(wn + j * 16 + l15) * 32 + quad * 8];
#pragma unroll
        for (int i = 0; i < 4; ++i)
#pragma unroll
            for (int j = 0; j < 4; ++j)
                acc[i][j] = __builtin_amdgcn_mfma_f32_16x16x32_bf16(af[i], bfr[j], acc[i][j], 0, 0, 0);
        __syncthreads();
    }

    // ---- epilogue ----
    float bv4[4];
#pragma unroll
    for (int j = 0; j < 4; ++j)
        bv4[j] = biasCat[section * HD_ + sec_col0 + wn + j * 16 + l15];
#pragma unroll
    for (int i = 0; i < 4; ++i)
#pragma unroll
        for (int j = 0; j < 4; ++j)
#pragma unroll
            for (int r = 0; r < 4; ++r)
                acc[i][j][r] += bv4[j];

    if (section <= 1) {
        // L2-normalize each output row over this wave's 64 cols (= one head)
#pragma unroll
        for (int i = 0; i < 4; ++i)
#pragma unroll
            for (int r = 0; r < 4; ++r) {
                float s = 0.f;
#pragma unroll
                for (int j = 0; j < 4; ++j) s += acc[i][j][r] * acc[i][j][r];
                s += __shfl_xor(s, 1, 64);
                s += __shfl_xor(s, 2, 64);
                s += __shfl_xor(s, 4, 64);
                s += __shfl_xor(s, 8, 64);
                float scl = rsqrtf(s);
#pragma unroll
                for (int j = 0; j < 4; ++j) acc[i][j][r] *= scl;
            }
    }
    if (section >= 1) {
        float* sums = (section == 1) ? ksum : vsum;
#pragma unroll
        for (int j = 0; j < 4; ++j) {
            float cs = 0.f;
#pragma unroll
            for (int i = 0; i < 4; ++i)
#pragma unroll
                for (int r = 0; r < 4; ++r) cs += acc[i][j][r];
            cs += __shfl_xor(cs, 16, 64);
            cs += __shfl_xor(cs, 32, 64);
            if (quad == 0)
                atomicAdd(&sums[b * HD_ + sec_col0 + wn + j * 16 + l15], cs);
        }
    }

    bhalf* outp = (section == 0) ? qn : (section == 1 ? kn : vv);
#pragma unroll
    for (int i = 0; i < 4; ++i)
#pragma unroll
        for (int r = 0; r < 4; ++r) {
            size_t row = (size_t)(row0 + wm + i * 16 + quad * 4 + r);
#pragma unroll
            for (int j = 0; j < 4; ++j)
                outp[row * HD_ + sec_col0 + wn + j * 16 + l15] = f2bf(acc[i][j][r]);
        }
}

// ---------------------------------------------------------------------------
// K2: kvs[b,h,m,d] = sum_l kn[b,l,h,m] * v[b,l,h,d]   (MFMA, split-L atomics)
//     block = (bh, l-chunk of 1024); 4 waves split each 128-l subtile.
// ---------------------------------------------------------------------------
__global__ __launch_bounds__(256) void kv_kernel(
    const bhalf* __restrict__ kn, const bhalf* __restrict__ vv,
    float* __restrict__ kvs)
{
    const int bh = blockIdx.x & 63;
    const int ls = blockIdx.x >> 6;      // 0..15
    const int b = bh >> 3, h = bh & 7;
    const int l0blk = ls * 1024;

    __shared__ bhalf Ks[128 * 66];       // stride 66 -> conflict-free u16 gathers
    __shared__ bhalf Vs[128 * 66];
    __shared__ float kvsL[64 * 64];

    const int tid = threadIdx.x;
    const int wave = tid >> 6, lane = tid & 63;
    const int l15 = lane & 15, quad = lane >> 4;

    for (int i = tid; i < 4096; i += 256) kvsL[i] = 0.f;

    f32x4 acc[4][4];
#pragma unroll
    for (int i = 0; i < 4; ++i)
#pragma unroll
        for (int j = 0; j < 4; ++j)
            acc[i][j] = (f32x4)(0.0f);

    const int srow = tid & 127;          // staging row within 128-l chunk
    const int scol = (tid >> 7) * 32;    // 0 or 32

    for (int ch = 0; ch < 8; ++ch) {
        int l0 = l0blk + ch * 128;
        {
            size_t gbase = ((size_t)(b * N_ + l0 + srow)) * HD_ + h * D_ + scol;
            const uint4* ksrc = (const uint4*)(kn + gbase);
            const uint4* vsrc = (const uint4*)(vv + gbase);
#pragma unroll
            for (int q4 = 0; q4 < 4; ++q4) {
                uint4 kw = ksrc[q4];
                uint4 vw = vsrc[q4];
                unsigned* kd = (unsigned*)&Ks[srow * 66 + scol + q4 * 8];
                unsigned* vd = (unsigned*)&Vs[srow * 66 + scol + q4 * 8];
                kd[0] = kw.x; kd[1] = kw.y; kd[2] = kw.z; kd[3] = kw.w;
                vd[0] = vw.x; vd[1] = vw.y; vd[2] = vw.z; vd[3] = vw.w;
            }
        }
        __syncthreads();

        const int lrow = wave * 32 + quad * 8;
        short8 af[4], bfr[4];
#pragma unroll
        for (int i = 0; i < 4; ++i) {
            short8 t;
#pragma unroll
            for (int jj = 0; jj < 8; ++jj)
                t[jj] = (short)Ks[(lrow + jj) * 66 + i * 16 + l15];   // A[m][l] gather
            af[i] = t;
        }
#pragma unroll
        for (int j = 0; j < 4; ++j) {
            short8 t;
#pragma unroll
            for (int jj = 0; jj < 8; ++jj)
                t[jj] = (short)Vs[(lrow + jj) * 66 + j * 16 + l15];   // B[l][d] gather
            bfr[j] = t;
        }
#pragma unroll
        for (int i = 0; i < 4; ++i)
#pragma unroll
            for (int j = 0; j < 4; ++j)
                acc[i][j] = __builtin_amdgcn_mfma_f32_16x16x32_bf16(af[i], bfr[j], acc[i][j], 0, 0, 0);
        __syncthreads();
    }

    // wave partials -> LDS -> global atomics
#pragma unroll
    for (int i = 0; i < 4; ++i)
#pragma unroll
        for (int j = 0; j < 4; ++j)
#pragma unroll
            for (int r = 0; r < 4; ++r)
                atomicAdd(&kvsL[(i * 16 + quad * 4 + r) * 64 + j * 16 + l15], acc[i][j][r]);
    __syncthreads();
    float* kvg = kvs + (size_t)bh * 4096;
    for (int i = tid; i < 4096; i += 256) atomicAdd(&kvg[i], kvsL[i]);
}

// ---------------------------------------------------------------------------
// K3: out[row,d] = (1/8) * sum_h (q_h . kvs_h[:,d] + N*vsum_h[d]) / (q_h . ksum_h + 2N)
//     block = 64 rows, 8 waves = 8 heads, kvs head-slice in 64 VGPRs/lane.
// ---------------------------------------------------------------------------
__global__ __launch_bounds__(512) void attn_kernel(
    const bhalf* __restrict__ qn, const float* __restrict__ kvs,
    const float* __restrict__ ksum, const float* __restrict__ vsum,
    float* __restrict__ out)
{
    const int row0 = blockIdx.x * 64;
    const int b = row0 >> 14;
    const int tid = threadIdx.x;
    const int h = tid >> 6;              // wave index = head
    const int lane = tid & 63;           // = output dim d

    __shared__ bhalf qS[64 * 512];
    __shared__ float outS[64 * 64];

    // stage 64 rows of q (bf16)
    {
        int r = tid >> 3, c0 = (tid & 7) * 64;
        const uint4* src = (const uint4*)(qn + (size_t)(row0 + r) * HD_ + c0);
        uint4* dst = (uint4*)&qS[r * 512 + c0];
#pragma unroll
        for (int q4 = 0; q4 < 8; ++q4) dst[q4] = src[q4];
    }
    for (int i = tid; i < 4096; i += 512) outS[i] = 0.f;

    // per-wave registers: kvs[h][m][lane], ksum/vsum lane slices
    float kv[64];
    {
        const float* kvg = kvs + ((size_t)(b * 8 + h)) * 4096;
#pragma unroll
        for (int m = 0; m < 64; ++m) kv[m] = kvg[m * 64 + lane];
    }
    const float ks_l = ksum[b * HD_ + h * 64 + lane];
    const float vs_l = vsum[b * HD_ + h * 64 + lane];

    __syncthreads();

    for (int r = 0; r < 64; ++r) {
        float qv = bf2f(qS[r * 512 + h * 64 + lane]);
        // denominator: q_h . ksum_h + 2N (butterfly over 64 lanes)
        float dp = qv * ks_l;
        dp += __shfl_xor(dp, 1, 64);
        dp += __shfl_xor(dp, 2, 64);
        dp += __shfl_xor(dp, 4, 64);
        dp += __shfl_xor(dp, 8, 64);
        dp += __shfl_xor(dp, 16, 64);
        dp += __shfl_xor(dp, 32, 64);
        float den = dp + 2.0f * NF;
        // numerator: N*vsum + sum_m q_m * kvs[m][lane]
        float accv = NF * vs_l;
#pragma unroll
        for (int m = 0; m < 64; ++m)
            accv += __shfl(qv, m, 64) * kv[m];
        atomicAdd(&outS[r * 64 + lane], accv / den);
    }
    __syncthreads();
    for (int i = tid; i < 4096; i += 512)
        out[(size_t)row0 * 64 + i] = outS[i] * 0.125f;
}

// ---------------------------------------------------------------------------
// Workspace layout (bytes):
//   qn   @ 0          : 131072*512*2 = 134217728
//   kn   @ 134217728  : 134217728
//   vv   @ 268435456  : 134217728
//   WT   @ 402653184  : 1536*256*2   = 786432
//   bias @ 403439616  : 1536*4       = 6144
//   ksum @ 403445760  : 8*512*4      = 16384
//   vsum @ 403462144  : 16384
//   kvs  @ 403478528  : 64*4096*4    = 1048576
// Total ~405 MB.
// ---------------------------------------------------------------------------
extern "C" void kernel_launch(void* const* d_in, const int* in_sizes, int n_in,
                              void* d_out, int out_size, void* d_ws, size_t ws_size,
                              hipStream_t stream)
{
    const float* query  = (const float*)d_in[0];
    const float* source = (const float*)d_in[1];
    const float* Wq = (const float*)d_in[2];
    const float* bq = (const float*)d_in[3];
    const float* Wk = (const float*)d_in[4];
    const float* bk = (const float*)d_in[5];
    const float* Wv = (const float*)d_in[6];
    const float* bv = (const float*)d_in[7];

    char* ws = (char*)d_ws;
    bhalf* qn      = (bhalf*)(ws + 0);
    bhalf* kn      = (bhalf*)(ws + 134217728);
    bhalf* vv      = (bhalf*)(ws + 268435456);
    bhalf* WT      = (bhalf*)(ws + 402653184);
    float* biasCat = (float*)(ws + 403439616);
    float* ksum    = (float*)(ws + 403445760);
    float* vsum    = (float*)(ws + 403462144);
    float* kvs     = (float*)(ws + 403478528);

    // zero the accumulators (ksum, vsum, kvs are contiguous)
    hipMemsetAsync(ws + 403445760, 0, 16384 + 16384 + 1048576, stream);

    cast_w_kernel<<<1536, 256, 0, stream>>>(Wq, Wk, Wv, bq, bk, bv, WT, biasCat);
    proj_kernel<<<dim3(12, 1024), 256, 0, stream>>>(query, source, WT, biasCat,
                                                    qn, kn, vv, ksum, vsum);
    kv_kernel<<<1024, 256, 0, stream>>>(kn, vv, kvs);
    attn_kernel<<<2048, 512, 0, stream>>>(qn, kvs, ksum, vsum, (float*)d_out);
}

// Round 2
// 838.888 us; speedup vs baseline: 2.2091x; 2.2091x over previous
//
#include <hip/hip_runtime.h>

// Problem constants
#define B_   8
#define N_   16384
#define C_   256
#define H_   8
#define D_   64
#define HD_  512
#define BN_  (B_ * N_)          // 131072 total rows
#define NF   16384.0f

typedef __attribute__((ext_vector_type(8))) short short8;   // 8 bf16 (4 VGPRs)
typedef __attribute__((ext_vector_type(4))) float f32x4;    // MFMA accumulator

typedef unsigned short bhalf;   // raw bf16 bits

__device__ __forceinline__ bhalf f2bf(float x) {
    union { float f; unsigned u; } v; v.f = x;
    unsigned r = v.u + 0x7fffu + ((v.u >> 16) & 1u);   // RNE
    return (bhalf)(r >> 16);
}
__device__ __forceinline__ float bf2f(bhalf h) {
    union { unsigned u; float f; } v; v.u = ((unsigned)h) << 16;
    return v.f;
}

// ---------------------------------------------------------------------------
// K0: cast + transpose weights:  WT[c][k] = W_sec[k][c_sec]  (c = sec*512+cs)
//     and concat biases (fp32).
// ---------------------------------------------------------------------------
__global__ void cast_w_kernel(const float* __restrict__ Wq, const float* __restrict__ Wk,
                              const float* __restrict__ Wv, const float* __restrict__ bq,
                              const float* __restrict__ bk, const float* __restrict__ bv,
                              bhalf* __restrict__ WT, float* __restrict__ biasCat)
{
    int c = blockIdx.x;              // 0..1535
    int k = threadIdx.x;             // 0..255
    int sec = c >> 9, cs = c & 511;
    const float* W = (sec == 0) ? Wq : (sec == 1 ? Wk : Wv);
    WT[(size_t)c * C_ + k] = f2bf(W[(size_t)k * HD_ + cs]);
    if (k == 0) {
        const float* bb = (sec == 0) ? bq : (sec == 1 ? bk : bv);
        biasCat[c] = bb[cs];
    }
}

// ---------------------------------------------------------------------------
// K1: projection GEMM  out[row, col] = A[row,:] @ W[:, col] + bias
//     grid.x = 12 col-tiles (0..3 -> q, 4..7 -> k, 8..11 -> v), grid.y = 1024 row-tiles
//     Epilogue: bias, per-head L2 norm (q,k), ksum/vsum atomics (k,v), bf16 store.
// ---------------------------------------------------------------------------
__global__ __launch_bounds__(256) void proj_kernel(
    const float* __restrict__ query, const float* __restrict__ source,
    const bhalf* __restrict__ WT, const float* __restrict__ biasCat,
    bhalf* __restrict__ qn, bhalf* __restrict__ kn, bhalf* __restrict__ vv,
    float* __restrict__ ksum, float* __restrict__ vsum)
{
    const int ct = blockIdx.x;           // 0..11
    const int rt = blockIdx.y;           // 0..1023
    const int section = ct >> 2;         // 0=q, 1=k, 2=v
    const int sec_col0 = (ct & 3) * 128; // col offset within 512-wide section
    const int row0 = rt * 128;
    const int b = row0 >> 14;            // 16384 rows per batch

    const float* Abase = (section == 0 ? query : source) + (size_t)row0 * C_;
    const bhalf* Wbase = WT + (size_t)(section * HD_ + sec_col0) * C_;

    __shared__ bhalf As[128 * 32];
    __shared__ bhalf Bs[128 * 32];

    const int tid  = threadIdx.x;
    const int wave = tid >> 6;
    const int lane = tid & 63;
    const int l15  = lane & 15;
    const int quad = lane >> 4;
    const int wm = (wave >> 1) * 64;     // wave row offset in tile
    const int wn = (wave & 1) * 64;      // wave col offset in tile

    f32x4 acc[4][4];
#pragma unroll
    for (int i = 0; i < 4; ++i)
#pragma unroll
        for (int j = 0; j < 4; ++j)
            acc[i][j] = (f32x4)(0.0f);

    const int sr = tid >> 1;             // staging row 0..127
    const int sc = (tid & 1) * 16;       // staging col 0 or 16 (of 32)

    for (int kk = 0; kk < C_; kk += 32) {
        // stage A tile (fp32 global -> bf16 LDS), 16 elems/thread
        {
            const float* src = Abase + (size_t)sr * C_ + kk + sc;
            float tmp[16];
            *(float4*)&tmp[0]  = *(const float4*)(src + 0);
            *(float4*)&tmp[4]  = *(const float4*)(src + 4);
            *(float4*)&tmp[8]  = *(const float4*)(src + 8);
            *(float4*)&tmp[12] = *(const float4*)(src + 12);
            bhalf* dst = &As[sr * 32 + sc];
#pragma unroll
            for (int e = 0; e < 16; ++e) dst[e] = f2bf(tmp[e]);
        }
        // stage B tile (bf16 copy), 16 elems/thread
        {
            const uint4* s4 = (const uint4*)(Wbase + (size_t)sr * C_ + kk + sc);
            uint4* d4 = (uint4*)&Bs[sr * 32 + sc];
            d4[0] = s4[0]; d4[1] = s4[1];
        }
        __syncthreads();

        short8 af[4], bfr[4];
#pragma unroll
        for (int i = 0; i < 4; ++i)
            af[i] = *(const short8*)&As[(wm + i * 16 + l15) * 32 + quad * 8];
#pragma unroll
        for (int j = 0; j < 4; ++j)
            bfr[j] = *(const short8*)&Bs[(wn + j * 16 + l15) * 32 + quad * 8];
#pragma unroll
        for (int i = 0; i < 4; ++i)
#pragma unroll
            for (int j = 0; j < 4; ++j)
                acc[i][j] = __builtin_amdgcn_mfma_f32_16x16x32_bf16(af[i], bfr[j], acc[i][j], 0, 0, 0);
        __syncthreads();
    }

    // ---- epilogue ----
    float bv4[4];
#pragma unroll
    for (int j = 0; j < 4; ++j)
        bv4[j] = biasCat[section * HD_ + sec_col0 + wn + j * 16 + l15];
#pragma unroll
    for (int i = 0; i < 4; ++i)
#pragma unroll
        for (int j = 0; j < 4; ++j)
#pragma unroll
            for (int r = 0; r < 4; ++r)
                acc[i][j][r] += bv4[j];

    if (section <= 1) {
        // L2-normalize each output row over this wave's 64 cols (= one head)
#pragma unroll
        for (int i = 0; i < 4; ++i)
#pragma unroll
            for (int r = 0; r < 4; ++r) {
                float s = 0.f;
#pragma unroll
                for (int j = 0; j < 4; ++j) s += acc[i][j][r] * acc[i][j][r];
                s += __shfl_xor(s, 1, 64);
                s += __shfl_xor(s, 2, 64);
                s += __shfl_xor(s, 4, 64);
                s += __shfl_xor(s, 8, 64);
                float scl = rsqrtf(s);
#pragma unroll
                for (int j = 0; j < 4; ++j) acc[i][j][r] *= scl;
            }
    }
    if (section >= 1) {
        float* sums = (section == 1) ? ksum : vsum;
#pragma unroll
        for (int j = 0; j < 4; ++j) {
            float cs = 0.f;
#pragma unroll
            for (int i = 0; i < 4; ++i)
#pragma unroll
                for (int r = 0; r < 4; ++r) cs += acc[i][j][r];
            cs += __shfl_xor(cs, 16, 64);
            cs += __shfl_xor(cs, 32, 64);
            if (quad == 0)
                atomicAdd(&sums[b * HD_ + sec_col0 + wn + j * 16 + l15], cs);
        }
    }

    bhalf* outp = (section == 0) ? qn : (section == 1 ? kn : vv);
#pragma unroll
    for (int i = 0; i < 4; ++i)
#pragma unroll
        for (int r = 0; r < 4; ++r) {
            size_t row = (size_t)(row0 + wm + i * 16 + quad * 4 + r);
#pragma unroll
            for (int j = 0; j < 4; ++j)
                outp[row * HD_ + sec_col0 + wn + j * 16 + l15] = f2bf(acc[i][j][r]);
        }
}

// ---------------------------------------------------------------------------
// K2: kvs[b,h,m,d] = sum_l kn[b,l,h,m] * v[b,l,h,d]   (MFMA, split-L atomics)
//     block = (bh, l-chunk of 1024); 4 waves split each 128-l subtile.
// ---------------------------------------------------------------------------
__global__ __launch_bounds__(256) void kv_kernel(
    const bhalf* __restrict__ kn, const bhalf* __restrict__ vv,
    float* __restrict__ kvs)
{
    const int bh = blockIdx.x & 63;
    const int ls = blockIdx.x >> 6;      // 0..15
    const int b = bh >> 3, h = bh & 7;
    const int l0blk = ls * 1024;

    __shared__ bhalf Ks[128 * 66];       // stride 66 -> conflict-free u16 gathers
    __shared__ bhalf Vs[128 * 66];
    __shared__ float kvsL[64 * 64];

    const int tid = threadIdx.x;
    const int wave = tid >> 6, lane = tid & 63;
    const int l15 = lane & 15, quad = lane >> 4;

    for (int i = tid; i < 4096; i += 256) kvsL[i] = 0.f;

    f32x4 acc[4][4];
#pragma unroll
    for (int i = 0; i < 4; ++i)
#pragma unroll
        for (int j = 0; j < 4; ++j)
            acc[i][j] = (f32x4)(0.0f);

    const int srow = tid & 127;          // staging row within 128-l chunk
    const int scol = (tid >> 7) * 32;    // 0 or 32

    for (int ch = 0; ch < 8; ++ch) {
        int l0 = l0blk + ch * 128;
        {
            size_t gbase = ((size_t)(b * N_ + l0 + srow)) * HD_ + h * D_ + scol;
            const uint4* ksrc = (const uint4*)(kn + gbase);
            const uint4* vsrc = (const uint4*)(vv + gbase);
#pragma unroll
            for (int q4 = 0; q4 < 4; ++q4) {
                uint4 kw = ksrc[q4];
                uint4 vw = vsrc[q4];
                unsigned* kd = (unsigned*)&Ks[srow * 66 + scol + q4 * 8];
                unsigned* vd = (unsigned*)&Vs[srow * 66 + scol + q4 * 8];
                kd[0] = kw.x; kd[1] = kw.y; kd[2] = kw.z; kd[3] = kw.w;
                vd[0] = vw.x; vd[1] = vw.y; vd[2] = vw.z; vd[3] = vw.w;
            }
        }
        __syncthreads();

        const int lrow = wave * 32 + quad * 8;
        short8 af[4], bfr[4];
#pragma unroll
        for (int i = 0; i < 4; ++i) {
            short8 t;
#pragma unroll
            for (int jj = 0; jj < 8; ++jj)
                t[jj] = (short)Ks[(lrow + jj) * 66 + i * 16 + l15];   // A[m][l] gather
            af[i] = t;
        }
#pragma unroll
        for (int j = 0; j < 4; ++j) {
            short8 t;
#pragma unroll
            for (int jj = 0; jj < 8; ++jj)
                t[jj] = (short)Vs[(lrow + jj) * 66 + j * 16 + l15];   // B[l][d] gather
            bfr[j] = t;
        }
#pragma unroll
        for (int i = 0; i < 4; ++i)
#pragma unroll
            for (int j = 0; j < 4; ++j)
                acc[i][j] = __builtin_amdgcn_mfma_f32_16x16x32_bf16(af[i], bfr[j], acc[i][j], 0, 0, 0);
        __syncthreads();
    }

    // wave partials -> LDS -> global atomics
#pragma unroll
    for (int i = 0; i < 4; ++i)
#pragma unroll
        for (int j = 0; j < 4; ++j)
#pragma unroll
            for (int r = 0; r < 4; ++r)
                atomicAdd(&kvsL[(i * 16 + quad * 4 + r) * 64 + j * 16 + l15], acc[i][j][r]);
    __syncthreads();
    float* kvg = kvs + (size_t)bh * 4096;
    for (int i = tid; i < 4096; i += 256) atomicAdd(&kvg[i], kvsL[i]);
}

// ---------------------------------------------------------------------------
// K2b: build augmented bf16 B-matrices for the epilogue GEMM:
//      Btb[bh][n][k] (n=0..79, k=0..63):
//        n < 64 : kvs[b,h,k,n]   (transposed so k is contiguous per n-row)
//        n == 64: ksum[b,h,k]    (normalizer folded in as an extra column)
//        n > 64 : 0              (pad to n-tile multiple of 16)
// ---------------------------------------------------------------------------
__global__ void prep_b_kernel(const float* __restrict__ kvs,
                              const float* __restrict__ ksum,
                              bhalf* __restrict__ Btb)
{
    const int bh = blockIdx.x;           // 0..63
    const int b = bh >> 3, h = bh & 7;
    const float* kvg = kvs + (size_t)bh * 4096;
    const float* ksg = ksum + b * HD_ + h * 64;
    bhalf* o = Btb + (size_t)bh * 80 * 64;
    for (int idx = threadIdx.x; idx < 80 * 64; idx += 256) {
        int n = idx >> 6, k = idx & 63;
        float val = (n < 64) ? kvg[k * 64 + n] : (n == 64 ? ksg[k] : 0.0f);
        o[idx] = f2bf(val);
    }
}

// ---------------------------------------------------------------------------
// K3: epilogue via MFMA. Per wave: 32 rows; per head: num(+den) = q @ Bt^T
//     (20 mfma over K=64, 5 n-tiles incl. augmented den column), then
//     out_acc += (num + N*vsum) / (den + 2N). No LDS; A-frags straight from
//     global (4 quads x 2 k-steps cover each row's contiguous 128B head
//     slice -> full line utilization), B-frags are L2 hits (640 KB hot set).
// ---------------------------------------------------------------------------
__global__ __launch_bounds__(256) void attn_kernel(
    const bhalf* __restrict__ qn, const bhalf* __restrict__ Btb,
    const float* __restrict__ vsum, float* __restrict__ out)
{
    const int tid  = threadIdx.x;
    const int wave = tid >> 6;
    const int lane = tid & 63;
    const int l15  = lane & 15;
    const int quad = lane >> 4;
    const int row0 = blockIdx.x * 128 + wave * 32;   // 32 rows per wave
    const int b = row0 >> 14;

    f32x4 outacc[2][4];
#pragma unroll
    for (int i = 0; i < 2; ++i)
#pragma unroll
        for (int j = 0; j < 4; ++j)
            outacc[i][j] = (f32x4)(0.0f);

#pragma unroll
    for (int h = 0; h < 8; ++h) {
        // A fragments: rows row0 + i*16 + l15, cols h*64 + kk*32 + quad*8
        short8 af[2][2];
#pragma unroll
        for (int i = 0; i < 2; ++i)
#pragma unroll
            for (int kk = 0; kk < 2; ++kk)
                af[i][kk] = *(const short8*)(qn +
                    (size_t)(row0 + i * 16 + l15) * HD_ + h * 64 + kk * 32 + quad * 8);

        // B fragments: Btb[bh][n=j*16+l15][k=kk*32+quad*8 ..+8]
        const bhalf* Bb = Btb + (size_t)(b * 8 + h) * 80 * 64;
        short8 bfr[5][2];
#pragma unroll
        for (int j = 0; j < 5; ++j)
#pragma unroll
            for (int kk = 0; kk < 2; ++kk)
                bfr[j][kk] = *(const short8*)(Bb + (j * 16 + l15) * 64 + kk * 32 + quad * 8);

        f32x4 nacc[2][5];
#pragma unroll
        for (int i = 0; i < 2; ++i)
#pragma unroll
            for (int j = 0; j < 5; ++j)
                nacc[i][j] = (f32x4)(0.0f);
#pragma unroll
        for (int kk = 0; kk < 2; ++kk)
#pragma unroll
            for (int i = 0; i < 2; ++i)
#pragma unroll
                for (int j = 0; j < 5; ++j)
                    nacc[i][j] = __builtin_amdgcn_mfma_f32_16x16x32_bf16(
                        af[i][kk], bfr[j][kk], nacc[i][j], 0, 0, 0);

        // vsum for this lane's columns
        float vsv[4];
#pragma unroll
        for (int j = 0; j < 4; ++j)
            vsv[j] = vsum[b * HD_ + h * 64 + j * 16 + l15];

        // den lives in col 64 = n-tile 4, held by lanes with l15==0 (lane quad*16)
#pragma unroll
        for (int i = 0; i < 2; ++i)
#pragma unroll
            for (int r = 0; r < 4; ++r) {
                float den = __shfl(nacc[i][4][r], quad << 4, 64) + 2.0f * NF;
                float rden = 1.0f / den;
#pragma unroll
                for (int j = 0; j < 4; ++j)
                    outacc[i][j][r] += (nacc[i][j][r] + NF * vsv[j]) * rden;
            }
    }

    // store: out[row][d], row = row0 + i*16 + quad*4 + r, d = j*16 + l15
#pragma unroll
    for (int i = 0; i < 2; ++i)
#pragma unroll
        for (int r = 0; r < 4; ++r) {
            size_t row = (size_t)(row0 + i * 16 + quad * 4 + r);
#pragma unroll
            for (int j = 0; j < 4; ++j)
                out[row * D_ + j * 16 + l15] = outacc[i][j][r] * 0.125f;
        }
}

// ---------------------------------------------------------------------------
// Workspace layout (bytes):
//   qn   @ 0          : 131072*512*2 = 134217728
//   kn   @ 134217728  : 134217728
//   vv   @ 268435456  : 134217728
//   WT   @ 402653184  : 1536*256*2   = 786432
//   bias @ 403439616  : 1536*4       = 6144
//   ksum @ 403445760  : 8*512*4      = 16384
//   vsum @ 403462144  : 16384
//   kvs  @ 403478528  : 64*4096*4    = 1048576
//   Btb  @ 404527104  : 64*80*64*2   = 655360
// Total ~405.2 MB.
// ---------------------------------------------------------------------------
extern "C" void kernel_launch(void* const* d_in, const int* in_sizes, int n_in,
                              void* d_out, int out_size, void* d_ws, size_t ws_size,
                              hipStream_t stream)
{
    const float* query  = (const float*)d_in[0];
    const float* source = (const float*)d_in[1];
    const float* Wq = (const float*)d_in[2];
    const float* bq = (const float*)d_in[3];
    const float* Wk = (const float*)d_in[4];
    const float* bk = (const float*)d_in[5];
    const float* Wv = (const float*)d_in[6];
    const float* bv = (const float*)d_in[7];

    char* ws = (char*)d_ws;
    bhalf* qn      = (bhalf*)(ws + 0);
    bhalf* kn      = (bhalf*)(ws + 134217728);
    bhalf* vv      = (bhalf*)(ws + 268435456);
    bhalf* WT      = (bhalf*)(ws + 402653184);
    float* biasCat = (float*)(ws + 403439616);
    float* ksum    = (float*)(ws + 403445760);
    float* vsum    = (float*)(ws + 403462144);
    float* kvs     = (float*)(ws + 403478528);
    bhalf* Btb     = (bhalf*)(ws + 404527104);

    // zero the accumulators (ksum, vsum, kvs are contiguous)
    hipMemsetAsync(ws + 403445760, 0, 16384 + 16384 + 1048576, stream);

    cast_w_kernel<<<1536, 256, 0, stream>>>(Wq, Wk, Wv, bq, bk, bv, WT, biasCat);
    proj_kernel<<<dim3(12, 1024), 256, 0, stream>>>(query, source, WT, biasCat,
                                                    qn, kn, vv, ksum, vsum);
    kv_kernel<<<1024, 256, 0, stream>>>(kn, vv, kvs);
    prep_b_kernel<<<64, 256, 0, stream>>>(kvs, ksum, Btb);
    attn_kernel<<<1024, 256, 0, stream>>>(qn, Btb, vsum, (float*)d_out);
}

// Round 3
// 694.557 us; speedup vs baseline: 2.6681x; 1.2078x over previous
//
#include <hip/hip_runtime.h>

// Problem constants
#define B_   8
#define N_   16384
#define C_   256
#define H_   8
#define D_   64
#define HD_  512
#define NF   16384.0f

#define AP   280   // As pitch in shorts (560 B: 16B-aligned rows, bank-uniform b128)
#define SP   136   // kS/vS/qS pitch in shorts (272 B: 16B-aligned, bank-uniform b128)

typedef __attribute__((ext_vector_type(8))) short short8;   // 8 bf16 (4 VGPRs)
typedef __attribute__((ext_vector_type(4))) float f32x4;    // MFMA accumulator

typedef unsigned short bhalf;   // raw bf16 bits

__device__ __forceinline__ bhalf f2bf(float x) {
    union { float f; unsigned u; } v; v.f = x;
    unsigned r = v.u + 0x7fffu + ((v.u >> 16) & 1u);   // RNE
    return (bhalf)(r >> 16);
}
__device__ __forceinline__ float bf2f(bhalf h) {
    union { unsigned u; float f; } v; v.u = ((unsigned)h) << 16;
    return v.f;
}

// ---------------------------------------------------------------------------
// K0: cast + transpose weights:  WT[c][k] = W_sec[k][c_sec]  (c = sec*512+cs)
//     and concat biases (fp32). WT is k-contiguous -> B-fragments are 16B
//     lane loads straight from L2 (weights = 768 KB, always hot).
// ---------------------------------------------------------------------------
__global__ void cast_w_kernel(const float* __restrict__ Wq, const float* __restrict__ Wk,
                              const float* __restrict__ Wv, const float* __restrict__ bq,
                              const float* __restrict__ bk, const float* __restrict__ bv,
                              bhalf* __restrict__ WT, float* __restrict__ biasCat)
{
    int c = blockIdx.x;              // 0..1535
    int k = threadIdx.x;             // 0..255
    int sec = c >> 9, cs = c & 511;
    const float* W = (sec == 0) ? Wq : (sec == 1 ? Wk : Wv);
    WT[(size_t)c * C_ + k] = f2bf(W[(size_t)k * HD_ + cs]);
    if (k == 0) {
        const float* bb = (sec == 0) ? bq : (sec == 1 ? bk : bv);
        biasCat[c] = bb[cs];
    }
}

// ---------------------------------------------------------------------------
// K1: fused source pipeline. Per block: 512 source rows (4 subtiles of 128).
//  Per subtile: stage A once (fp32->bf16 LDS); per head-pair hp:
//    k-proj + v-proj MFMA (shared A-frags, B from L2) -> bias ->
//    L2-norm(k rows) -> ksum/vsum atomics -> store k,v transposed to LDS
//    ([feature][l]) -> kv-aggregation MFMA (K=128) accumulated in registers.
//  One kvs atomicAdd flush per block. kn/vv never touch HBM.
// ---------------------------------------------------------------------------
__global__ __launch_bounds__(256, 1) void proj_kv_kernel(
    const float* __restrict__ source, const bhalf* __restrict__ WT,
    const float* __restrict__ biasCat, float* __restrict__ ksum,
    float* __restrict__ vsum, float* __restrict__ kvs)
{
    __shared__ bhalf As[128 * AP];
    __shared__ bhalf kS[128 * SP];   // [2-head features 128][l 128]
    __shared__ bhalf vS[128 * SP];

    const int tid  = threadIdx.x;
    const int wave = tid >> 6;
    const int lane = tid & 63;
    const int l15  = lane & 15;
    const int quad = lane >> 4;
    const int wr   = wave >> 1;      // proj row-half
    const int wc   = wave & 1;       // proj col-half / kv head-local
    const int base_row = blockIdx.x * 512;
    const int b = base_row >> 14;    // whole block inside one batch (512 | 16384)
    const int mh = wr * 32;          // kv m-half

    f32x4 kvacc[4][2][4];
#pragma unroll
    for (int hp = 0; hp < 4; ++hp)
#pragma unroll
        for (int mi = 0; mi < 2; ++mi)
#pragma unroll
            for (int dj = 0; dj < 4; ++dj)
                kvacc[hp][mi][dj] = (f32x4)(0.0f);

    for (int rt = 0; rt < 4; ++rt) {
        const int row0 = base_row + rt * 128;
        __syncthreads();             // As free of previous-subtile readers
        {   // stage A subtile: 128 rows x 256 K, fp32 -> bf16
            const int sr = tid >> 1, sco = (tid & 1) * 16;
            const float* srcp = source + (size_t)(row0 + sr) * C_ + sco;
#pragma unroll
            for (int kk = 0; kk < 8; ++kk) {
                float t[16];
                *(float4*)&t[0]  = *(const float4*)(srcp + kk * 32 + 0);
                *(float4*)&t[4]  = *(const float4*)(srcp + kk * 32 + 4);
                *(float4*)&t[8]  = *(const float4*)(srcp + kk * 32 + 8);
                *(float4*)&t[12] = *(const float4*)(srcp + kk * 32 + 12);
                bhalf hh[16];
#pragma unroll
                for (int e = 0; e < 16; ++e) hh[e] = f2bf(t[e]);
                *(uint4*)&As[sr * AP + kk * 32 + sco]     = *(uint4*)&hh[0];
                *(uint4*)&As[sr * AP + kk * 32 + sco + 8] = *(uint4*)&hh[8];
            }
        }
        __syncthreads();

        for (int hp = 0; hp < 4; ++hp) {
            f32x4 acck[4][4], accv[4][4];
#pragma unroll
            for (int i = 0; i < 4; ++i)
#pragma unroll
                for (int j = 0; j < 4; ++j) {
                    acck[i][j] = (f32x4)(0.0f);
                    accv[i][j] = (f32x4)(0.0f);
                }
            const int colb = hp * 128 + wc * 64;       // col within 512-section
            const bhalf* WK = WT + (size_t)(HD_ + colb) * C_;
            const bhalf* WV = WT + (size_t)(2 * HD_ + colb) * C_;
#pragma unroll
            for (int ks = 0; ks < 8; ++ks) {
                short8 af[4];
#pragma unroll
                for (int i = 0; i < 4; ++i)
                    af[i] = *(const short8*)&As[(wr * 64 + i * 16 + l15) * AP + ks * 32 + quad * 8];
                short8 bk8[4], bv8[4];
#pragma unroll
                for (int j = 0; j < 4; ++j) {
                    bk8[j] = *(const short8*)(WK + (size_t)(j * 16 + l15) * C_ + ks * 32 + quad * 8);
                    bv8[j] = *(const short8*)(WV + (size_t)(j * 16 + l15) * C_ + ks * 32 + quad * 8);
                }
#pragma unroll
                for (int i = 0; i < 4; ++i)
#pragma unroll
                    for (int j = 0; j < 4; ++j) {
                        acck[i][j] = __builtin_amdgcn_mfma_f32_16x16x32_bf16(af[i], bk8[j], acck[i][j], 0, 0, 0);
                        accv[i][j] = __builtin_amdgcn_mfma_f32_16x16x32_bf16(af[i], bv8[j], accv[i][j], 0, 0, 0);
                    }
            }
            // bias
#pragma unroll
            for (int j = 0; j < 4; ++j) {
                float bkj = biasCat[HD_ + colb + j * 16 + l15];
                float bvj = biasCat[2 * HD_ + colb + j * 16 + l15];
#pragma unroll
                for (int i = 0; i < 4; ++i)
#pragma unroll
                    for (int r = 0; r < 4; ++r) {
                        acck[i][j][r] += bkj;
                        accv[i][j][r] += bvj;
                    }
            }
            // L2-normalize k rows over the wave's 64 cols (= one head)
#pragma unroll
            for (int i = 0; i < 4; ++i)
#pragma unroll
                for (int r = 0; r < 4; ++r) {
                    float s = 0.f;
#pragma unroll
                    for (int j = 0; j < 4; ++j) s += acck[i][j][r] * acck[i][j][r];
                    s += __shfl_xor(s, 1, 64);
                    s += __shfl_xor(s, 2, 64);
                    s += __shfl_xor(s, 4, 64);
                    s += __shfl_xor(s, 8, 64);
                    float scl = rsqrtf(s);
#pragma unroll
                    for (int j = 0; j < 4; ++j) acck[i][j][r] *= scl;
                }
            // ksum / vsum column sums (over this wave's 64 rows)
#pragma unroll
            for (int j = 0; j < 4; ++j) {
                float csk = 0.f, csv = 0.f;
#pragma unroll
                for (int i = 0; i < 4; ++i)
#pragma unroll
                    for (int r = 0; r < 4; ++r) { csk += acck[i][j][r]; csv += accv[i][j][r]; }
                csk += __shfl_xor(csk, 16, 64);
                csk += __shfl_xor(csk, 32, 64);
                csv += __shfl_xor(csv, 16, 64);
                csv += __shfl_xor(csv, 32, 64);
                if (quad == 0) {
                    atomicAdd(&ksum[b * HD_ + colb + j * 16 + l15], csk);
                    atomicAdd(&vsum[b * HD_ + colb + j * 16 + l15], csv);
                }
            }
            // store transposed [feature][l]: lane's 4 r-values are contiguous l -> b64
#pragma unroll
            for (int i = 0; i < 4; ++i)
#pragma unroll
                for (int j = 0; j < 4; ++j) {
                    uint2 uk, uv;
                    uk.x = (unsigned)f2bf(acck[i][j][0]) | ((unsigned)f2bf(acck[i][j][1]) << 16);
                    uk.y = (unsigned)f2bf(acck[i][j][2]) | ((unsigned)f2bf(acck[i][j][3]) << 16);
                    uv.x = (unsigned)f2bf(accv[i][j][0]) | ((unsigned)f2bf(accv[i][j][1]) << 16);
                    uv.y = (unsigned)f2bf(accv[i][j][2]) | ((unsigned)f2bf(accv[i][j][3]) << 16);
                    int feat = wc * 64 + j * 16 + l15;
                    int lofs = wr * 64 + i * 16 + quad * 4;
                    *(uint2*)&kS[feat * SP + lofs] = uk;
                    *(uint2*)&vS[feat * SP + lofs] = uv;
                }
            __syncthreads();
            // kv aggregation: kv[m][d] += sum_l k[m][l]*v[l][d], K=128
#pragma unroll
            for (int k2 = 0; k2 < 4; ++k2) {
                short8 ak[2];
#pragma unroll
                for (int mi = 0; mi < 2; ++mi)
                    ak[mi] = *(const short8*)&kS[(wc * 64 + mh + mi * 16 + l15) * SP + k2 * 32 + quad * 8];
                short8 bv2[4];
#pragma unroll
                for (int dj = 0; dj < 4; ++dj)
                    bv2[dj] = *(const short8*)&vS[(wc * 64 + dj * 16 + l15) * SP + k2 * 32 + quad * 8];
#pragma unroll
                for (int mi = 0; mi < 2; ++mi)
#pragma unroll
                    for (int dj = 0; dj < 4; ++dj)
                        kvacc[hp][mi][dj] = __builtin_amdgcn_mfma_f32_16x16x32_bf16(
                            ak[mi], bv2[dj], kvacc[hp][mi][dj], 0, 0, 0);
            }
            __syncthreads();
        }
    }
    // flush kv partials
#pragma unroll
    for (int hp = 0; hp < 4; ++hp) {
        float* kvg = kvs + (size_t)(b * 8 + hp * 2 + wc) * 4096;
#pragma unroll
        for (int mi = 0; mi < 2; ++mi)
#pragma unroll
            for (int dj = 0; dj < 4; ++dj)
#pragma unroll
                for (int r = 0; r < 4; ++r)
                    atomicAdd(&kvg[(mh + mi * 16 + quad * 4 + r) * 64 + dj * 16 + l15],
                              kvacc[hp][mi][dj][r]);
    }
}

// ---------------------------------------------------------------------------
// K2b: build augmented bf16 B-matrices for the epilogue GEMM:
//      Btb[bh][n][k]: n<64 -> kvs[b,h,k,n]; n==64 -> ksum[b,h,k]; n>64 -> 0.
// ---------------------------------------------------------------------------
__global__ void prep_b_kernel(const float* __restrict__ kvs,
                              const float* __restrict__ ksum,
                              bhalf* __restrict__ Btb)
{
    const int bh = blockIdx.x;           // 0..63
    const int b = bh >> 3, h = bh & 7;
    const float* kvg = kvs + (size_t)bh * 4096;
    const float* ksg = ksum + b * HD_ + h * 64;
    bhalf* o = Btb + (size_t)bh * 80 * 64;
    for (int idx = threadIdx.x; idx < 80 * 64; idx += 256) {
        int n = idx >> 6, k = idx & 63;
        float val = (n < 64) ? kvg[k * 64 + n] : (n == 64 ? ksg[k] : 0.0f);
        o[idx] = f2bf(val);
    }
}

// ---------------------------------------------------------------------------
// K3: fused query pipeline. Per block: 128 query rows. Stage A once; per
//     chunk (2 heads): q-proj MFMA -> bias -> L2-norm -> qS LDS; then the
//     augmented-GEMM epilogue (B from L2, den = col 64 via shfl), out acc
//     in registers across all 8 heads. qn never touches HBM.
// ---------------------------------------------------------------------------
__global__ __launch_bounds__(256, 1) void qattn_kernel(
    const float* __restrict__ query, const bhalf* __restrict__ WT,
    const float* __restrict__ biasCat, const bhalf* __restrict__ Btb,
    const float* __restrict__ vsum, float* __restrict__ out)
{
    __shared__ bhalf As[128 * AP];
    __shared__ bhalf qS[128 * SP];   // [row][2-head cols]

    const int tid  = threadIdx.x;
    const int wave = tid >> 6;
    const int lane = tid & 63;
    const int l15  = lane & 15;
    const int quad = lane >> 4;
    const int wr   = wave >> 1;
    const int wc   = wave & 1;
    const int row0 = blockIdx.x * 128;
    const int b = row0 >> 14;

    {   // stage A tile
        const int sr = tid >> 1, sco = (tid & 1) * 16;
        const float* srcp = query + (size_t)(row0 + sr) * C_ + sco;
#pragma unroll
        for (int kk = 0; kk < 8; ++kk) {
            float t[16];
            *(float4*)&t[0]  = *(const float4*)(srcp + kk * 32 + 0);
            *(float4*)&t[4]  = *(const float4*)(srcp + kk * 32 + 4);
            *(float4*)&t[8]  = *(const float4*)(srcp + kk * 32 + 8);
            *(float4*)&t[12] = *(const float4*)(srcp + kk * 32 + 12);
            bhalf hh[16];
#pragma unroll
            for (int e = 0; e < 16; ++e) hh[e] = f2bf(t[e]);
            *(uint4*)&As[sr * AP + kk * 32 + sco]     = *(uint4*)&hh[0];
            *(uint4*)&As[sr * AP + kk * 32 + sco + 8] = *(uint4*)&hh[8];
        }
    }
    __syncthreads();

    f32x4 outacc[2][4];
#pragma unroll
    for (int i = 0; i < 2; ++i)
#pragma unroll
        for (int j = 0; j < 4; ++j)
            outacc[i][j] = (f32x4)(0.0f);

    for (int ch = 0; ch < 4; ++ch) {
        // ---- q-projection for heads 2ch, 2ch+1 ----
        f32x4 acc[4][4];
#pragma unroll
        for (int i = 0; i < 4; ++i)
#pragma unroll
            for (int j = 0; j < 4; ++j)
                acc[i][j] = (f32x4)(0.0f);
        const int colb = ch * 128 + wc * 64;
        const bhalf* WQ = WT + (size_t)colb * C_;
#pragma unroll
        for (int ks = 0; ks < 8; ++ks) {
            short8 af[4];
#pragma unroll
            for (int i = 0; i < 4; ++i)
                af[i] = *(const short8*)&As[(wr * 64 + i * 16 + l15) * AP + ks * 32 + quad * 8];
            short8 bq8[4];
#pragma unroll
            for (int j = 0; j < 4; ++j)
                bq8[j] = *(const short8*)(WQ + (size_t)(j * 16 + l15) * C_ + ks * 32 + quad * 8);
#pragma unroll
            for (int i = 0; i < 4; ++i)
#pragma unroll
                for (int j = 0; j < 4; ++j)
                    acc[i][j] = __builtin_amdgcn_mfma_f32_16x16x32_bf16(af[i], bq8[j], acc[i][j], 0, 0, 0);
        }
#pragma unroll
        for (int j = 0; j < 4; ++j) {
            float bj = biasCat[colb + j * 16 + l15];
#pragma unroll
            for (int i = 0; i < 4; ++i)
#pragma unroll
                for (int r = 0; r < 4; ++r) acc[i][j][r] += bj;
        }
#pragma unroll
        for (int i = 0; i < 4; ++i)
#pragma unroll
            for (int r = 0; r < 4; ++r) {
                float s = 0.f;
#pragma unroll
                for (int j = 0; j < 4; ++j) s += acc[i][j][r] * acc[i][j][r];
                s += __shfl_xor(s, 1, 64);
                s += __shfl_xor(s, 2, 64);
                s += __shfl_xor(s, 4, 64);
                s += __shfl_xor(s, 8, 64);
                float scl = rsqrtf(s);
#pragma unroll
                for (int j = 0; j < 4; ++j) acc[i][j][r] *= scl;
            }
        // store normalized q chunk row-major to LDS
#pragma unroll
        for (int i = 0; i < 4; ++i)
#pragma unroll
            for (int j = 0; j < 4; ++j)
#pragma unroll
                for (int r = 0; r < 4; ++r)
                    qS[(wr * 64 + i * 16 + quad * 4 + r) * SP + wc * 64 + j * 16 + l15]
                        = f2bf(acc[i][j][r]);
        __syncthreads();

        // ---- attention epilogue for the 2 heads of this chunk ----
#pragma unroll
        for (int hl = 0; hl < 2; ++hl) {
            const int h = ch * 2 + hl;
            const bhalf* Bb = Btb + (size_t)(b * 8 + h) * 80 * 64;
            short8 af2[2][2];
#pragma unroll
            for (int i = 0; i < 2; ++i)
#pragma unroll
                for (int kk = 0; kk < 2; ++kk)
                    af2[i][kk] = *(const short8*)&qS[(wave * 32 + i * 16 + l15) * SP
                                                     + hl * 64 + kk * 32 + quad * 8];
            short8 bfr[5][2];
#pragma unroll
            for (int j = 0; j < 5; ++j)
#pragma unroll
                for (int kk = 0; kk < 2; ++kk)
                    bfr[j][kk] = *(const short8*)(Bb + (j * 16 + l15) * 64 + kk * 32 + quad * 8);
            f32x4 nacc[2][5];
#pragma unroll
            for (int i = 0; i < 2; ++i)
#pragma unroll
                for (int j = 0; j < 5; ++j)
                    nacc[i][j] = (f32x4)(0.0f);
#pragma unroll
            for (int kk = 0; kk < 2; ++kk)
#pragma unroll
                for (int i = 0; i < 2; ++i)
#pragma unroll
                    for (int j = 0; j < 5; ++j)
                        nacc[i][j] = __builtin_amdgcn_mfma_f32_16x16x32_bf16(
                            af2[i][kk], bfr[j][kk], nacc[i][j], 0, 0, 0);
            float vsv[4];
#pragma unroll
            for (int j = 0; j < 4; ++j)
                vsv[j] = vsum[b * HD_ + h * 64 + j * 16 + l15];
#pragma unroll
            for (int i = 0; i < 2; ++i)
#pragma unroll
                for (int r = 0; r < 4; ++r) {
                    float den = __shfl(nacc[i][4][r], quad << 4, 64) + 2.0f * NF;
                    float rden = 1.0f / den;
#pragma unroll
                    for (int j = 0; j < 4; ++j)
                        outacc[i][j][r] += (nacc[i][j][r] + NF * vsv[j]) * rden;
                }
        }
        __syncthreads();
    }

    // store: out[row][d]
#pragma unroll
    for (int i = 0; i < 2; ++i)
#pragma unroll
        for (int r = 0; r < 4; ++r) {
            size_t row = (size_t)(row0 + wave * 32 + i * 16 + quad * 4 + r);
#pragma unroll
            for (int j = 0; j < 4; ++j)
                out[row * D_ + j * 16 + l15] = outacc[i][j][r] * 0.125f;
        }
}

// ---------------------------------------------------------------------------
// Workspace layout (bytes):
//   WT   @ 0       : 1536*256*2 = 786432
//   bias @ 786432  : 6144
//   ksum @ 792576  : 16384
//   vsum @ 808960  : 16384
//   kvs  @ 825344  : 1048576
//   Btb  @ 1873920 : 655360
// Total ~2.4 MB (down from 405 MB).
// ---------------------------------------------------------------------------
extern "C" void kernel_launch(void* const* d_in, const int* in_sizes, int n_in,
                              void* d_out, int out_size, void* d_ws, size_t ws_size,
                              hipStream_t stream)
{
    const float* query  = (const float*)d_in[0];
    const float* source = (const float*)d_in[1];
    const float* Wq = (const float*)d_in[2];
    const float* bq = (const float*)d_in[3];
    const float* Wk = (const float*)d_in[4];
    const float* bk = (const float*)d_in[5];
    const float* Wv = (const float*)d_in[6];
    const float* bv = (const float*)d_in[7];

    char* ws = (char*)d_ws;
    bhalf* WT      = (bhalf*)(ws + 0);
    float* biasCat = (float*)(ws + 786432);
    float* ksum    = (float*)(ws + 792576);
    float* vsum    = (float*)(ws + 808960);
    float* kvs     = (float*)(ws + 825344);
    bhalf* Btb     = (bhalf*)(ws + 1873920);

    // zero the accumulators (ksum, vsum, kvs are contiguous)
    hipMemsetAsync(ws + 792576, 0, 16384 + 16384 + 1048576, stream);

    cast_w_kernel<<<1536, 256, 0, stream>>>(Wq, Wk, Wv, bq, bk, bv, WT, biasCat);
    proj_kv_kernel<<<256, 256, 0, stream>>>(source, WT, biasCat, ksum, vsum, kvs);
    prep_b_kernel<<<64, 256, 0, stream>>>(kvs, ksum, Btb);
    qattn_kernel<<<1024, 256, 0, stream>>>(query, WT, biasCat, Btb, vsum, (float*)d_out);
}